// Round 6
// baseline (2783.817 us; speedup 1.0000x reference)
//
#include <hip/hip_runtime.h>

typedef unsigned short u16;
typedef unsigned long long u64;
typedef __attribute__((ext_vector_type(8))) short short8;
typedef __attribute__((ext_vector_type(4))) float floatx4;
typedef __attribute__((ext_vector_type(4))) float f32x4;
typedef __attribute__((ext_vector_type(4))) int intx4;

#define LOG2PI_F 1.8378770664093453f
#define LOG2E_F 1.4426950408889634f
#define TWOLOG2E_F 2.8853900817779268f

__device__ inline float bf2f(u16 u) { return __uint_as_float(((unsigned)u) << 16); }
__device__ inline u16 f2bf(float f) {
  unsigned u = __float_as_uint(f);
  u += 0x7fff + ((u >> 16) & 1);   // RTNE
  return (u16)(u >> 16);
}
__device__ inline int q127(float f) {
  int qv = __float2int_rn(f * 127.f);
  return qv > 127 ? 127 : (qv < -127 ? -127 : qv);
}

// ---------------------------------------------------------------- prep: casts / adds / copies
struct PrepArgs {
  const float* src[18];
  const float* src2[18];
  void* dst[18];
  int mode[18];     // 0: f32->bf16, 1: f32+f32->f32, 2: f32 copy
  int n[18];
  int blk0[19];
  int nseg;
};

__global__ __launch_bounds__(256) void k_prep(PrepArgs a) {
  int b = blockIdx.x, s = 0;
  while (s + 1 < a.nseg && b >= a.blk0[s + 1]) ++s;
  int i = (b - a.blk0[s]) * 1024 + threadIdx.x * 4;
  if (i >= a.n[s]) return;
  if (a.mode[s] == 0) {
    f32x4 v = *(const f32x4*)(a.src[s] + i);
    u64 p = (u64)f2bf(v[0]) | ((u64)f2bf(v[1]) << 16)
          | ((u64)f2bf(v[2]) << 32) | ((u64)f2bf(v[3]) << 48);
    *(u64*)((u16*)a.dst[s] + i) = p;
  } else if (a.mode[s] == 1) {
    f32x4 x = *(const f32x4*)(a.src[s] + i);
    f32x4 y = *(const f32x4*)(a.src2[s] + i);
    *(f32x4*)((float*)a.dst[s] + i) = x + y;
  } else {
    *(f32x4*)((float*)a.dst[s] + i) = *(const f32x4*)(a.src[s] + i);
  }
}

// ---------------------------------------------------------------- Whh per-row int8 quantization
// sr = max/(127*127) * sign/log2e-fold: -log2e for i/f/o gates, +2*log2e for g gate.
__global__ __launch_bounds__(256) void k_quant(const float* __restrict__ w0,
                                               const float* __restrict__ w1,
                                               char* __restrict__ q, float* __restrict__ sr) {
  int tid = threadIdx.x, lane = tid & 63;
  int row = blockIdx.x * 4 + (tid >> 6);
  int br = row >> 10, r = row & 1023;
  const float* src = (br ? w1 : w0) + (size_t)r * 256 + lane * 4;
  f32x4 v = *(const f32x4*)src;
  float m = fmaxf(fmaxf(fabsf(v[0]), fabsf(v[1])), fmaxf(fabsf(v[2]), fabsf(v[3])));
#pragma unroll
  for (int o = 32; o >= 1; o >>= 1) m = fmaxf(m, __shfl_xor(m, o));
  float inv = m > 0.f ? 127.f / m : 0.f;
  int pk = 0;
#pragma unroll
  for (int c = 0; c < 4; ++c) {
    int qq = __float2int_rn(v[c] * inv);
    qq = qq > 127 ? 127 : (qq < -127 ? -127 : qq);
    pk |= (qq & 255) << (8 * c);
  }
  *(int*)(q + (size_t)row * 256 + lane * 4) = pk;
  if (lane == 0) {
    float sf = (r >= 512 && r < 768) ? TWOLOG2E_F : -LOG2E_F;
    sr[row] = m * (1.f / (127.f * 127.f)) * sf;
  }
}

// ---------------------------------------------------------------- GEMM: C = act(A @ W^T + bias), z = branch
template <int EPI, int AF32>
__global__ __launch_bounds__(256, 2) void k_gemm(
    const void* __restrict__ Agv, const u16* __restrict__ Wg,
    const float* __restrict__ biasP, void* __restrict__ outv,
    int Nn, int K, int relu, int Tseg,
    long az, long wz, long oz) {
  __shared__ u16 As[128][72];
  __shared__ u16 Ws[128][72];
  const int tid = threadIdx.x;
  const int z = blockIdx.z;
  const int bn = blockIdx.x * 128;
  const int bm = blockIdx.y * 128;
  const int w = tid >> 6, lane = tid & 63, lm = lane & 15, lq = lane >> 4;
  const int wr = (w >> 1) * 64, wc = (w & 1) * 64;
  const int tr = tid >> 3, tc = (tid & 7) * 8;

  const u16* Ab = (const u16*)Agv;
  const float* Af = (const float*)Agv;
  const u16* Wb = Wg + (size_t)z * wz;

  floatx4 acc[4][4] = {};

  for (int k0 = 0; k0 < K; k0 += 64) {
    __syncthreads();
#pragma unroll
    for (int rr = 0; rr < 4; ++rr) {
      int row = rr * 32 + tr;
      if (AF32) {
        const float* src = Af + (size_t)z * az + (size_t)(bm + row) * K + k0 + tc;
        f32x4 v0 = *(const f32x4*)src;
        f32x4 v1 = *(const f32x4*)(src + 4);
        short8 sv;
#pragma unroll
        for (int c = 0; c < 4; ++c) { sv[c] = (short)f2bf(v0[c]); sv[4 + c] = (short)f2bf(v1[c]); }
        *(short8*)&As[row][tc] = sv;
      } else {
        *(short8*)&As[row][tc] = *(const short8*)(Ab + (size_t)z * az + (size_t)(bm + row) * K + k0 + tc);
      }
      *(short8*)&Ws[row][tc] = *(const short8*)(Wb + (size_t)(bn + row) * K + k0 + tc);
    }
    __syncthreads();
#pragma unroll
    for (int kk = 0; kk < 2; ++kk) {
      short8 a4[4], b4[4];
#pragma unroll
      for (int i = 0; i < 4; ++i) {
        a4[i] = *(const short8*)&As[wr + i * 16 + lm][kk * 32 + lq * 8];
        b4[i] = *(const short8*)&Ws[wc + i * 16 + lm][kk * 32 + lq * 8];
      }
#pragma unroll
      for (int i = 0; i < 4; ++i)
#pragma unroll
        for (int j = 0; j < 4; ++j)
          acc[i][j] = __builtin_amdgcn_mfma_f32_16x16x32_bf16(a4[i], b4[j], acc[i][j], 0, 0, 0);
    }
  }

#pragma unroll
  for (int i = 0; i < 4; ++i) {
#pragma unroll
    for (int j = 0; j < 4; ++j) {
      int col = bn + wc + j * 16 + lm;
      float bv = biasP[(size_t)z * Nn + col];
      float v[4];
#pragma unroll
      for (int r = 0; r < 4; ++r) {
        float t = acc[i][j][r] + bv;
        v[r] = relu ? fmaxf(t, 0.f) : t;
      }
      int row0l = bm + wr + i * 16 + lq * 4;
      if (EPI == 1) {
        u16* o = (u16*)outv + (size_t)z * oz;
#pragma unroll
        for (int r = 0; r < 4; ++r) o[(size_t)(row0l + r) * Nn + col] = f2bf(v[r]);
      } else {
        // gin frame layout [bbx][Tseg][4 mq][1024 col][4 row]: packed u64 = 4 batch rows
        // at same col -> coalesced 128B/quarter-wave stores (round-5 scalar layout was
        // store-issue-bound: +75us/launch). gate-fold: i/f/o * -log2e, g * +2*log2e.
        float s = (col >= 512 && col < 768) ? TWOLOG2E_F : -LOG2E_F;
        int t_l = row0l >> 8;
        int bfull = row0l & 255;
        int bbx = bfull >> 4;
        int mq = (bfull >> 2) & 3;
        u64 p = (u64)f2bf(v[0] * s) | ((u64)f2bf(v[1] * s) << 16)
              | ((u64)f2bf(v[2] * s) << 32) | ((u64)f2bf(v[3] * s) << 48);
        u16* o = (u16*)outv + (size_t)z * oz;
        size_t idx = ((((size_t)bbx * Tseg + t_l) * 4 + mq) * 1024 + col) * 4;
        *(u64*)(o + idx) = p;
      }
    }
  }
}

// ---------------------------------------------------------------- LayerNorm + relu -> bf16 (feature LN), z-batched
__global__ __launch_bounds__(256) void k_ln_relu(const u16* __restrict__ in,
                                                 const float* __restrict__ lnp,
                                                 u16* __restrict__ out,
                                                 long inz, long outz) {
  int z = blockIdx.y;
  int w = threadIdx.x >> 6, lane = threadIdx.x & 63;
  size_t row = (size_t)blockIdx.x * 4 + w;
  const u16* ip = in + (size_t)z * inz;
  u16* op = out + (size_t)z * outz;
  const float* gw = lnp + (size_t)z * 512;
  const float* gb = gw + 256;
  u64 hv = *(const u64*)(ip + row * 256 + lane * 4);
  float x[4];
#pragma unroll
  for (int c = 0; c < 4; ++c) x[c] = bf2f((u16)(hv >> (16 * c)));
  float s = x[0] + x[1] + x[2] + x[3];
  float q = x[0] * x[0] + x[1] * x[1] + x[2] * x[2] + x[3] * x[3];
#pragma unroll
  for (int o = 32; o >= 1; o >>= 1) { s += __shfl_xor(s, o); q += __shfl_xor(q, o); }
  float mean = s * (1.f / 256.f);
  float var = q * (1.f / 256.f) - mean * mean;
  float rs = rsqrtf(var + 1e-5f);
  u64 p = 0;
#pragma unroll
  for (int c = 0; c < 4; ++c) {
    int k = lane * 4 + c;
    float y = (x[c] - mean) * rs * gw[k] + gb[k];
    y = fmaxf(y, 0.f);
    p |= ((u64)f2bf(y)) << (16 * c);
  }
  *(u64*)(op + row * 256 + lane * 4) = p;
}

// ---------------------------------------------------------------- LSTM scan: wavefront over chain positions
// done[t]=1 resets h,c at START of step t => each row's window factors into independent
// chains (zero-start, or carry-start at window head). Per block (2 rows x 32 steps):
// build chains, sort by len desc; iteration p runs step p of every live chain as a DENSE
// M=16 gather-GEMM over an LDS h-store + dense cell update. No done-masking, no shuffles.
// h-store: [2 rows][34 slots][272B pitch] (slot0 = carry h quantized, slot33 = zeros,
// slot t+1 = h of step t). Row-major-outer: slot stride 272B = 68 dw = 4 (mod 32 banks)
// -> 16 gathered slots land 2-per-bank-offset (~conflict-free); the old [slot][row] order
// had stride 136 dw = 8 (mod 32) -> 4-way (869K conflicts/dispatch).
// c-store: [64 chains][260 f32 pitch] LDS, per-chain running c.
// gin: round-4 frame layout (coalesced GEMM writes); scan gathers (t*4+mq)*4096+jj*4+r0.
// End of kernel: bulk-dump h-store -> global hs in the frag layout k_head expects.
struct ScanArgs {
  const u16 *gin0, *gin1;       // [bbx16][Tseg][4 mq][1024][4] bf16 (sign/log2e folded)
  const char *whq0, *whq1;      // [1024][256] i8
  const float *sr0, *sr1;       // [1024] f32 row scales (folded)
  const float *h00, *h01, *c00, *c01;   // [256][256] f32
  char *hs0, *hs1;              // [Tseg][16 frames][4096] i8 frag-order
  float *hsv0, *hsv1, *csv0, *csv1;     // [256][256] f32
  const int* done;
  int t0, Tseg;                 // Tseg == 32
};

#define HPITCH 272
#define CPITCH 260
#define HSLOT(slot, row) ((((row) * 34) + (slot)) * HPITCH)
#define SCAN_LDS (34 * 2 * HPITCH + 64 * CPITCH * 4 + 80 * 4 + 33 * 4)

__global__ __launch_bounds__(1024, 1) void k_scan(ScanArgs A) {
  const int bb = blockIdx.x & 127, br = blockIdx.x >> 7;
  const int rb = bb << 1;                // 2 batch rows per block
  const int tid = threadIdx.x;
  const int w = tid >> 6, lane = tid & 63, lm = lane & 15, lq = lane >> 4;
  const int jj = w * 16 + lm;            // this lane's hidden unit
  const int mbase = (bb & 7) * 2;        // frame row base within bbx frame

  extern __shared__ char dsm[];
  char* hst = dsm;                                   // [2][34][HPITCH]
  float* cst = (float*)(dsm + 34 * 2 * HPITCH);      // [64][CPITCH]
  int* chinfo = (int*)(dsm + 34 * 2 * HPITCH + 64 * CPITCH * 4);  // [80]
  int* cnt = chinfo + 80;                            // [33]; cnt[32] = nchains

  const char* whq = br ? A.whq1 : A.whq0;
  const float* srP = br ? A.sr1 : A.sr0;
  const u16* gin = (br ? A.gin1 : A.gin0) + (size_t)(bb >> 3) * A.Tseg * 16384;
  const float* h0 = br ? A.h01 : A.h00;
  const float* c0 = br ? A.c01 : A.c00;
  char* hsg = (br ? A.hs1 : A.hs0) + (bb >> 3) * 4096;
  float* hsv = br ? A.hsv1 : A.hsv0;
  float* csv = br ? A.csv1 : A.csv0;
  const int lastT = A.Tseg - 1;

  // weight tiles VGPR-resident (64 regs): tile g -> gate rows g*256 + w*16 + lm
  intx4 wreg[4][4];
#pragma unroll
  for (int g = 0; g < 4; ++g)
#pragma unroll
    for (int kk = 0; kk < 4; ++kk)
      wreg[g][kk] =
          *(const intx4*)(whq + (size_t)(g * 256 + w * 16 + lm) * 256 + kk * 64 + lq * 16);

  float srw[4];
#pragma unroll
  for (int g = 0; g < 4; ++g) srw[g] = srP[g * 256 + jj];

  // ---- schedule build (wave 0): chains via ballot, rank-sort by len desc ----
  if (w == 0) {
    int row = lane >> 5, t = lane & 31;
    int dn = A.done[(size_t)(A.t0 + t) * 256 + rb + row];
    int isstart = (t == 0) || dn;
    u64 mask = __ballot(isstart ? 1 : 0);
    int desc = 0, key = -1;
    if (isstart) {
      u64 m2 = (lane == 63) ? 0ULL : (mask >> (lane + 1));
      int lim = (row + 1) * 32 - lane;   // distance to row end
      int d = lim;
      if (m2) { int z = (int)__ffsll((long long)m2); if (z < d) d = z; }
      int iszero = dn ? 1 : 0;           // t==0 && !done -> carry chain
      desc = t | (row << 8) | (iszero << 9) | (d << 16);
      key = (d << 8) | (63 - lane);
    }
    int rank = 0;
#pragma unroll 1
    for (int i = 0; i < 64; ++i) {
      int ok = __shfl(key, i);
      rank += (ok > key) ? 1 : 0;
    }
    if (isstart) chinfo[rank] = desc;
    int nch = __popcll(mask);
    for (int c = nch + lane; c < 80; c += 64)
      chinfo[c] = 0 | (0 << 8) | (1 << 9) | (0 << 16);   // safe pad: zero-type, len 0
    if (lane == 0) cnt[32] = nch;
  }
  // zero c-store
  for (int i = tid; i < 64 * CPITCH; i += 1024) cst[i] = 0.f;
  // h-store slot0 (carry h quantized) + slot33 (zeros)
  if (tid < 512) {
    int row = tid >> 8, j = tid & 255;
    float hv = h0[(size_t)(rb + row) * 256 + j];
    hst[HSLOT(0, row) + j] = (char)q127(hv);
    hst[HSLOT(33, row) + j] = 0;
  }
  __syncthreads();

  // cnt[p] = #chains with len > p; carry-chain c init
  {
    int nch = cnt[32];
    if (tid < 32) {
      int c2 = 0;
      for (int c = 0; c < nch; ++c) c2 += ((chinfo[c] >> 16) > tid) ? 1 : 0;
      cnt[tid] = c2;
    }
#pragma unroll 1
    for (int c04 = 0; c04 < 64; c04 += 4) {
      int c = c04 + (tid >> 8);
      if (c < nch) {
        int d = chinfo[c];
        if (((d >> 9) & 1) == 0 && (d & 255) == 0) {   // carry chain
          int row = (d >> 8) & 1, j = tid & 255;
          cst[c * CPITCH + j] = c0[(size_t)(rb + row) * 256 + j];
        }
      }
    }
  }
  __syncthreads();

  const int maxp = chinfo[0] >> 16;   // longest chain

  for (int p = 0; p < maxp; ++p) {
    int Ap = cnt[p];
#pragma unroll 1
    for (int tb = 0; tb < 64; tb += 16) {
      if (tb >= Ap) break;
      // A-gather descriptor for this lane's tile row (chain tb+lm)
      int dA = chinfo[tb + lm];
      int stA = dA & 255, rowA = (dA >> 8) & 1, zrA = (dA >> 9) & 1;
      int slot = (p == 0) ? (zrA ? 33 : 0) : (stA + p);
      int habase = HSLOT(slot, rowA);
      // per-r chain descs; issue gin + c loads early (hide latency under MFMA)
      int trr[4], rwr[4], crv[4];
      u16 gld[4][4];
      float cpr[4];
#pragma unroll
      for (int r = 0; r < 4; ++r) {
        int cr = tb + 4 * lq + r;
        crv[r] = cr;
        int dr = chinfo[cr];
        trr[r] = (dr & 255) + p;
        rwr[r] = (dr >> 8) & 1;
        int m16 = mbase + rwr[r];
        unsigned off = ((unsigned)(trr[r] * 4 + (m16 >> 2))) * 4096 + (unsigned)jj * 4 + (m16 & 3);
        gld[r][0] = gin[off];
        gld[r][1] = gin[off + 1024];
        gld[r][2] = gin[off + 2048];
        gld[r][3] = gin[off + 3072];
        cpr[r] = cst[cr * CPITCH + jj];
      }
      // dense MFMA: 16 x 16x16x64 i8 (A rows = 16 gathered chains)
      intx4 acc[4] = {};
#pragma unroll
      for (int kk = 0; kk < 4; ++kk) {
        intx4 af = *(const intx4*)&hst[habase + kk * 64 + lq * 16];
#pragma unroll
        for (int g = 0; g < 4; ++g)
          acc[g] = __builtin_amdgcn_mfma_i32_16x16x64_i8(af, wreg[g][kk], acc[g], 0, 0, 0);
      }
      // cells: lane handles chains tb+4lq+r (r=0..3), hidden jj, all gates in-register
#pragma unroll
      for (int r = 0; r < 4; ++r) {
        if (crv[r] < Ap) {
          float xi = fmaf((float)acc[0][r], srw[0], bf2f(gld[r][0]));
          float xf = fmaf((float)acc[1][r], srw[1], bf2f(gld[r][1]));
          float xg = fmaf((float)acc[2][r], srw[2], bf2f(gld[r][2]));
          float xo = fmaf((float)acc[3][r], srw[3], bf2f(gld[r][3]));
          float ig = __builtin_amdgcn_rcpf(1.f + __builtin_amdgcn_exp2f(xi));
          float fg = __builtin_amdgcn_rcpf(1.f + __builtin_amdgcn_exp2f(xf));
          float gg = 1.f - 2.f * __builtin_amdgcn_rcpf(1.f + __builtin_amdgcn_exp2f(xg));
          float og = __builtin_amdgcn_rcpf(1.f + __builtin_amdgcn_exp2f(xo));
          float cn = fg * cpr[r] + ig * gg;
          float th = 1.f - 2.f * __builtin_amdgcn_rcpf(1.f + __builtin_amdgcn_exp2f(TWOLOG2E_F * cn));
          float hn = og * th;
          cst[crv[r] * CPITCH + jj] = cn;
          hst[HSLOT(trr[r] + 1, rwr[r]) + jj] = (char)q127(hn);
          if (trr[r] == lastT) {
            size_t idx = (size_t)(rb + rwr[r]) * 256 + jj;
            hsv[idx] = hn;
            csv[idx] = cn;
          }
        }
      }
    }
    __syncthreads();   // h-store writes visible for next iteration's gathers
  }

  // bulk hs dump: slots 1..32 -> global frag layout (rows at m16 = (bb&7)*2 + row)
  {
    int t = tid >> 5, row = (tid >> 4) & 1, q = tid & 15;
    intx4 v = *(const intx4*)&hst[HSLOT(t + 1, row) + q * 16];
    char* dst = hsg + (size_t)t * 65536 + (q >> 2) * 1024 + (q & 3) * 256 + (mbase + row) * 16;
    *(intx4*)dst = v;
  }
}

// ---------------------------------------------------------------- heads: LN + policy/value + logprob/entropy
__global__ __launch_bounds__(256) void k_head(
    const char* __restrict__ hs_a, const char* __restrict__ hs_c,
    const float* __restrict__ a_lnw, const float* __restrict__ a_lnb,
    const float* __restrict__ c_lnw, const float* __restrict__ c_lnb,
    const float* __restrict__ mW, const float* __restrict__ mb,
    const float* __restrict__ logstd, const float* __restrict__ hW,
    const float* __restrict__ hb, const float* __restrict__ action,
    float* __restrict__ lp, float* __restrict__ ent, float* __restrict__ val,
    int row0) {
  __shared__ float smW[16][260];
  __shared__ float shW[256];
  __shared__ float spar[4][256];
  __shared__ float hrow[4][264];
  int tid = threadIdx.x;
  for (int i = tid; i < 4096; i += 256) smW[i >> 8][i & 255] = mW[i];
  shW[tid] = hW[tid];
  spar[0][tid] = a_lnw[tid]; spar[1][tid] = a_lnb[tid];
  spar[2][tid] = c_lnw[tid]; spar[3][tid] = c_lnb[tid];
  __syncthreads();

  int w = tid >> 6, lane = tid & 63, lm = lane & 15, lq = lane >> 4;
  float entc = 0.f;
#pragma unroll
  for (int j = 0; j < 16; ++j) entc += 0.5f + 0.5f * LOG2PI_F + logstd[j];
  float ls = logstd[lm];
  float sd = __expf(ls);
  float mbj = mb[lm];

  int rbase = (blockIdx.x * 4 + w) * 16;
  for (int rr = 0; rr < 16; ++rr) {
    int row = rbase + rr;
    int m = row & 15;
    size_t base = (size_t)(row >> 8) * 65536 + (size_t)((row >> 4) & 15) * 4096;
    int off = (lane >> 4) * 1024 + (m + 16 * ((lane >> 2) & 3)) * 16 + (lane & 3) * 4;
    int va = *(const int*)(hs_a + base + off);
    float x[4];
#pragma unroll
    for (int c = 0; c < 4; ++c) x[c] = (float)((va << (24 - 8 * c)) >> 24) * (1.f / 127.f);
    float s = x[0] + x[1] + x[2] + x[3];
    float q = x[0] * x[0] + x[1] * x[1] + x[2] * x[2] + x[3] * x[3];
#pragma unroll
    for (int o = 32; o >= 1; o >>= 1) { s += __shfl_xor(s, o); q += __shfl_xor(q, o); }
    float mean = s * (1.f / 256.f);
    float rs = rsqrtf(q * (1.f / 256.f) - mean * mean + 1e-5f);
    floatx4 hh;
#pragma unroll
    for (int c = 0; c < 4; ++c) {
      int k = lane * 4 + c;
      hh[c] = (x[c] - mean) * rs * spar[0][k] + spar[1][k];
    }
    *(floatx4*)&hrow[w][lane * 4] = hh;
    float p = 0.f;
#pragma unroll 16
    for (int k2 = 0; k2 < 64; ++k2) {
      int kx = lq * 64 + ((k2 + lq * 16) & 63);
      p = fmaf(hrow[w][kx], smW[lm][kx], p);
    }
    p += __shfl_xor(p, 16);
    p += __shfl_xor(p, 32);
    float meanj = p + mbj;
    float aj = action[(size_t)(row0 + row) * 16 + lm];
    float z = (aj - meanj) / sd;
    float term = -0.5f * z * z - ls - 0.5f * LOG2PI_F;
    term += __shfl_xor(term, 1);
    term += __shfl_xor(term, 2);
    term += __shfl_xor(term, 4);
    term += __shfl_xor(term, 8);
    int vc = *(const int*)(hs_c + base + off);
    float y[4];
#pragma unroll
    for (int c = 0; c < 4; ++c) y[c] = (float)((vc << (24 - 8 * c)) >> 24) * (1.f / 127.f);
    float s2 = y[0] + y[1] + y[2] + y[3];
    float q2 = y[0] * y[0] + y[1] * y[1] + y[2] * y[2] + y[3] * y[3];
#pragma unroll
    for (int o = 32; o >= 1; o >>= 1) { s2 += __shfl_xor(s2, o); q2 += __shfl_xor(q2, o); }
    float mean2 = s2 * (1.f / 256.f);
    float rs2 = rsqrtf(q2 * (1.f / 256.f) - mean2 * mean2 + 1e-5f);
    float pv = 0.f;
#pragma unroll
    for (int c = 0; c < 4; ++c) {
      int k = lane * 4 + c;
      float hc = (y[c] - mean2) * rs2 * spar[2][k] + spar[3][k];
      pv = fmaf(hc, shW[k], pv);
    }
#pragma unroll
    for (int o = 32; o >= 1; o >>= 1) pv += __shfl_xor(pv, o);
    if (lane == 0) {
      lp[row0 + row] = term;
      ent[row0 + row] = entc;
      val[row0 + row] = pv + hb[0];
    }
  }
}

// ---------------------------------------------------------------- host
extern "C" void kernel_launch(void* const* d_in, const int* in_sizes, int n_in,
                              void* d_out, int out_size, void* d_ws, size_t ws_size,
                              hipStream_t stream) {
  const int N = 131072, T = 512;
  const float* x = (const float*)d_in[0];
  const int* done = (const int*)d_in[1];
  const float* h0i[2] = {(const float*)d_in[2], (const float*)d_in[4]};
  const float* c0i[2] = {(const float*)d_in[3], (const float*)d_in[5]};
  const float* action = (const float*)d_in[6];
  const float *W1[2], *b1[2], *W2[2], *b2[2], *flnw[2], *flnb[2];
  const float *Wih[2], *Whh[2], *bih[2], *bhh[2], *lnw[2], *lnb[2];
  for (int br = 0; br < 2; ++br) {
    int o = 7 + br * 12;
    W1[br] = (const float*)d_in[o + 0];  b1[br] = (const float*)d_in[o + 1];
    W2[br] = (const float*)d_in[o + 2];  b2[br] = (const float*)d_in[o + 3];
    flnw[br] = (const float*)d_in[o + 4]; flnb[br] = (const float*)d_in[o + 5];
    Wih[br] = (const float*)d_in[o + 6]; Whh[br] = (const float*)d_in[o + 7];
    bih[br] = (const float*)d_in[o + 8]; bhh[br] = (const float*)d_in[o + 9];
    lnw[br] = (const float*)d_in[o + 10]; lnb[br] = (const float*)d_in[o + 11];
  }
  const float* mW = (const float*)d_in[31];
  const float* mb = (const float*)d_in[32];
  const float* logstd = (const float*)d_in[33];
  const float* hW = (const float*)d_in[34];
  const float* hb = (const float*)d_in[35];

  float* out = (float*)d_out;
  float* o_lp = out;
  float* o_ent = out + N;
  float* o_val = out + 2 * N;
  float* o_ah = out + 3 * N;
  float* o_ac = o_ah + 65536;
  float* o_ch = o_ac + 65536;
  float* o_cc = o_ch + 65536;

  const int sr = 16, st = 16;
  const long Ts = T / st, Ms = N / sr;

  char* pp = (char*)d_ws;
  auto carve = [&](size_t b) -> void* { void* r = pp; pp += (b + 255) & ~(size_t)255; return r; };
  u16* W1b = (u16*)carve(2 * 65536 * 2);
  u16* W2b = (u16*)carve(2 * 131072 * 2);
  u16* Wihb = (u16*)carve(2 * 262144 * 2);
  char* whhq = (char*)carve(2 * 262144);
  float* srowP = (float*)carve(2048 * 4);
  float* bihh = (float*)carve(2 * 1024 * 4);
  float* b1c = (float*)carve(2 * 512 * 4);
  float* b2c = (float*)carve(2 * 256 * 4);
  float* lnp = (float*)carve(1024 * 4);
  float* hsv = (float*)carve(2 * 65536 * 4);
  float* csv = (float*)carve(2 * 65536 * 4);
  u16* h1 = (u16*)carve((size_t)2 * Ms * 512 * 2);
  u16* g2 = (u16*)carve((size_t)2 * Ms * 256 * 2);
  u16* featP = (u16*)carve((size_t)2 * N * 256 * 2);
  u16* ginP = (u16*)carve((size_t)2 * Ts * 262144 * 2);
  char* hsbP = (char*)carve((size_t)2 * Ts * 65536);

  // prep
  PrepArgs pa{};
  int ns = 0, blk = 0;
  auto addseg = [&](const float* s1, const float* s2, void* d, int n, int mode) {
    pa.src[ns] = s1; pa.src2[ns] = s2; pa.dst[ns] = d; pa.mode[ns] = mode; pa.n[ns] = n;
    pa.blk0[ns] = blk; blk += (n + 1023) / 1024; ++ns;
  };
  for (int br = 0; br < 2; ++br) {
    addseg(W1[br], nullptr, W1b + br * 65536, 65536, 0);
    addseg(W2[br], nullptr, W2b + br * 131072, 131072, 0);
    addseg(Wih[br], nullptr, Wihb + br * 262144, 262144, 0);
    addseg(bih[br], bhh[br], bihh + br * 1024, 1024, 1);
    addseg(b1[br], nullptr, b1c + br * 512, 512, 2);
    addseg(b2[br], nullptr, b2c + br * 256, 256, 2);
    addseg(flnw[br], nullptr, lnp + br * 512, 256, 2);
    addseg(flnb[br], nullptr, lnp + br * 512 + 256, 256, 2);
  }
  pa.nseg = ns;
  pa.blk0[ns] = blk;
  k_prep<<<blk, 256, 0, stream>>>(pa);
  k_quant<<<512, 256, 0, stream>>>(Whh[0], Whh[1], whhq, srowP);

  // scan needs >64KB dynamic LDS
  hipFuncSetAttribute((const void*)&k_scan, hipFuncAttributeMaxDynamicSharedMemorySize,
                      ((SCAN_LDS + 255) & ~255));

  // MLP features (row-segmented, branch z-batched)
  for (int s = 0; s < sr; ++s) {
    k_gemm<1, 1><<<dim3(4, Ms / 128, 2), 256, 0, stream>>>(
        x + (size_t)s * Ms * 128, W1b, b1c, h1, 512, 128, 1, 0,
        0L, 65536L, (long)Ms * 512);
    k_gemm<1, 0><<<dim3(2, Ms / 128, 2), 256, 0, stream>>>(
        h1, W2b, b2c, g2, 256, 512, 0, 0,
        (long)Ms * 512, 131072L, (long)Ms * 256);
    k_ln_relu<<<dim3(Ms / 4, 2), 256, 0, stream>>>(
        g2, lnp, featP + (size_t)s * Ms * 256, (long)Ms * 256, (long)N * 256);
  }

  // gin precompute + scan + heads (time-segmented)
  for (int s = 0; s < st; ++s) {
    long t0 = s * Ts;
    k_gemm<2, 0><<<dim3(8, Ts * 2, 2), 256, 0, stream>>>(
        featP + (size_t)t0 * 65536, Wihb, bihh, ginP, 1024, 256, 0, (int)Ts,
        (long)N * 256, 262144L, Ts * 262144L);
    ScanArgs sa;
    sa.gin0 = ginP; sa.gin1 = ginP + Ts * 262144;
    sa.whq0 = whhq; sa.whq1 = whhq + 262144;
    sa.sr0 = srowP; sa.sr1 = srowP + 1024;
    sa.h00 = s ? hsv : h0i[0]; sa.h01 = s ? hsv + 65536 : h0i[1];
    sa.c00 = s ? csv : c0i[0]; sa.c01 = s ? csv + 65536 : c0i[1];
    sa.hs0 = hsbP; sa.hs1 = hsbP + Ts * 65536;
    bool last = (s == st - 1);
    sa.hsv0 = last ? o_ah : hsv; sa.hsv1 = last ? o_ch : hsv + 65536;
    sa.csv0 = last ? o_ac : csv; sa.csv1 = last ? o_cc : csv + 65536;
    sa.done = done; sa.t0 = (int)t0; sa.Tseg = (int)Ts;
    k_scan<<<256, 1024, ((SCAN_LDS + 255) & ~255), stream>>>(sa);
    k_head<<<(int)(Ts * 256 / 64), 256, 0, stream>>>(
        hsbP, hsbP + Ts * 65536, lnw[0], lnb[0], lnw[1], lnb[1],
        mW, mb, logstd, hW, hb, action,
        o_lp, o_ent, o_val, (int)(t0 * 256));
  }
}

// Round 7
// 2549.660 us; speedup vs baseline: 1.0918x; 1.0918x over previous
//
#include <hip/hip_runtime.h>

typedef unsigned short u16;
typedef unsigned long long u64;
typedef __attribute__((ext_vector_type(8))) short short8;
typedef __attribute__((ext_vector_type(4))) float floatx4;
typedef __attribute__((ext_vector_type(4))) float f32x4;
typedef __attribute__((ext_vector_type(4))) int intx4;

#define LOG2PI_F 1.8378770664093453f
#define LOG2E_F 1.4426950408889634f
#define TWOLOG2E_F 2.8853900817779268f

__device__ inline float bf2f(u16 u) { return __uint_as_float(((unsigned)u) << 16); }
__device__ inline u16 f2bf(float f) {
  unsigned u = __float_as_uint(f);
  u += 0x7fff + ((u >> 16) & 1);   // RTNE
  return (u16)(u >> 16);
}
__device__ inline int q127(float f) {
  int qv = __float2int_rn(f * 127.f);
  return qv > 127 ? 127 : (qv < -127 ? -127 : qv);
}

// ---------------------------------------------------------------- prep: casts / adds / copies
struct PrepArgs {
  const float* src[18];
  const float* src2[18];
  void* dst[18];
  int mode[18];     // 0: f32->bf16, 1: f32+f32->f32, 2: f32 copy
  int n[18];
  int blk0[19];
  int nseg;
};

__global__ __launch_bounds__(256) void k_prep(PrepArgs a) {
  int b = blockIdx.x, s = 0;
  while (s + 1 < a.nseg && b >= a.blk0[s + 1]) ++s;
  int i = (b - a.blk0[s]) * 1024 + threadIdx.x * 4;
  if (i >= a.n[s]) return;
  if (a.mode[s] == 0) {
    f32x4 v = *(const f32x4*)(a.src[s] + i);
    u64 p = (u64)f2bf(v[0]) | ((u64)f2bf(v[1]) << 16)
          | ((u64)f2bf(v[2]) << 32) | ((u64)f2bf(v[3]) << 48);
    *(u64*)((u16*)a.dst[s] + i) = p;
  } else if (a.mode[s] == 1) {
    f32x4 x = *(const f32x4*)(a.src[s] + i);
    f32x4 y = *(const f32x4*)(a.src2[s] + i);
    *(f32x4*)((float*)a.dst[s] + i) = x + y;
  } else {
    *(f32x4*)((float*)a.dst[s] + i) = *(const f32x4*)(a.src[s] + i);
  }
}

// ---------------------------------------------------------------- Whh per-row int8 quantization
// sr = max/(127*127) * sign/log2e-fold: -log2e for i/f/o gates, +2*log2e for g gate.
__global__ __launch_bounds__(256) void k_quant(const float* __restrict__ w0,
                                               const float* __restrict__ w1,
                                               char* __restrict__ q, float* __restrict__ sr) {
  int tid = threadIdx.x, lane = tid & 63;
  int row = blockIdx.x * 4 + (tid >> 6);
  int br = row >> 10, r = row & 1023;
  const float* src = (br ? w1 : w0) + (size_t)r * 256 + lane * 4;
  f32x4 v = *(const f32x4*)src;
  float m = fmaxf(fmaxf(fabsf(v[0]), fabsf(v[1])), fmaxf(fabsf(v[2]), fabsf(v[3])));
#pragma unroll
  for (int o = 32; o >= 1; o >>= 1) m = fmaxf(m, __shfl_xor(m, o));
  float inv = m > 0.f ? 127.f / m : 0.f;
  int pk = 0;
#pragma unroll
  for (int c = 0; c < 4; ++c) {
    int qq = __float2int_rn(v[c] * inv);
    qq = qq > 127 ? 127 : (qq < -127 ? -127 : qq);
    pk |= (qq & 255) << (8 * c);
  }
  *(int*)(q + (size_t)row * 256 + lane * 4) = pk;
  if (lane == 0) {
    float sf = (r >= 512 && r < 768) ? TWOLOG2E_F : -LOG2E_F;
    sr[row] = m * (1.f / (127.f * 127.f)) * sf;
  }
}

// ---------------------------------------------------------------- GEMM: C = act(A @ W^T + bias), z = branch
template <int EPI, int AF32>
__global__ __launch_bounds__(256, 2) void k_gemm(
    const void* __restrict__ Agv, const u16* __restrict__ Wg,
    const float* __restrict__ biasP, void* __restrict__ outv,
    int Nn, int K, int relu, int Tseg,
    long az, long wz, long oz) {
  __shared__ u16 As[128][72];
  __shared__ u16 Ws[128][72];
  const int tid = threadIdx.x;
  const int z = blockIdx.z;
  const int bn = blockIdx.x * 128;
  const int bm = blockIdx.y * 128;
  const int w = tid >> 6, lane = tid & 63, lm = lane & 15, lq = lane >> 4;
  const int wr = (w >> 1) * 64, wc = (w & 1) * 64;
  const int tr = tid >> 3, tc = (tid & 7) * 8;

  const u16* Ab = (const u16*)Agv;
  const float* Af = (const float*)Agv;
  const u16* Wb = Wg + (size_t)z * wz;

  floatx4 acc[4][4] = {};

  for (int k0 = 0; k0 < K; k0 += 64) {
    __syncthreads();
#pragma unroll
    for (int rr = 0; rr < 4; ++rr) {
      int row = rr * 32 + tr;
      if (AF32) {
        const float* src = Af + (size_t)z * az + (size_t)(bm + row) * K + k0 + tc;
        f32x4 v0 = *(const f32x4*)src;
        f32x4 v1 = *(const f32x4*)(src + 4);
        short8 sv;
#pragma unroll
        for (int c = 0; c < 4; ++c) { sv[c] = (short)f2bf(v0[c]); sv[4 + c] = (short)f2bf(v1[c]); }
        *(short8*)&As[row][tc] = sv;
      } else {
        *(short8*)&As[row][tc] = *(const short8*)(Ab + (size_t)z * az + (size_t)(bm + row) * K + k0 + tc);
      }
      *(short8*)&Ws[row][tc] = *(const short8*)(Wb + (size_t)(bn + row) * K + k0 + tc);
    }
    __syncthreads();
#pragma unroll
    for (int kk = 0; kk < 2; ++kk) {
      short8 a4[4], b4[4];
#pragma unroll
      for (int i = 0; i < 4; ++i) {
        a4[i] = *(const short8*)&As[wr + i * 16 + lm][kk * 32 + lq * 8];
        b4[i] = *(const short8*)&Ws[wc + i * 16 + lm][kk * 32 + lq * 8];
      }
#pragma unroll
      for (int i = 0; i < 4; ++i)
#pragma unroll
        for (int j = 0; j < 4; ++j)
          acc[i][j] = __builtin_amdgcn_mfma_f32_16x16x32_bf16(a4[i], b4[j], acc[i][j], 0, 0, 0);
    }
  }

#pragma unroll
  for (int i = 0; i < 4; ++i) {
#pragma unroll
    for (int j = 0; j < 4; ++j) {
      int col = bn + wc + j * 16 + lm;
      float bv = biasP[(size_t)z * Nn + col];
      float v[4];
#pragma unroll
      for (int r = 0; r < 4; ++r) {
        float t = acc[i][j][r] + bv;
        v[r] = relu ? fmaxf(t, 0.f) : t;
      }
      int row0l = bm + wr + i * 16 + lq * 4;
      if (EPI == 1) {
        u16* o = (u16*)outv + (size_t)z * oz;
#pragma unroll
        for (int r = 0; r < 4; ++r) o[(size_t)(row0l + r) * Nn + col] = f2bf(v[r]);
      } else {
        // gin: dense [t*256+row][1024] bf16 rows (scan gathers are 32B-contiguous per
        // quarter-wave; R6 A/B test proved these scalar stores cost ~nothing).
        // gate-fold: i/f/o * -log2e, g * +2*log2e (cell uses raw v_exp_f32 = 2^x).
        float s = (col >= 512 && col < 768) ? TWOLOG2E_F : -LOG2E_F;
        u16* o = (u16*)outv + (size_t)z * oz;
#pragma unroll
        for (int r = 0; r < 4; ++r) o[(size_t)(row0l + r) * Nn + col] = f2bf(v[r] * s);
      }
    }
  }
}

// ---------------------------------------------------------------- LayerNorm + relu -> bf16 (feature LN), z-batched
__global__ __launch_bounds__(256) void k_ln_relu(const u16* __restrict__ in,
                                                 const float* __restrict__ lnp,
                                                 u16* __restrict__ out,
                                                 long inz, long outz) {
  int z = blockIdx.y;
  int w = threadIdx.x >> 6, lane = threadIdx.x & 63;
  size_t row = (size_t)blockIdx.x * 4 + w;
  const u16* ip = in + (size_t)z * inz;
  u16* op = out + (size_t)z * outz;
  const float* gw = lnp + (size_t)z * 512;
  const float* gb = gw + 256;
  u64 hv = *(const u64*)(ip + row * 256 + lane * 4);
  float x[4];
#pragma unroll
  for (int c = 0; c < 4; ++c) x[c] = bf2f((u16)(hv >> (16 * c)));
  float s = x[0] + x[1] + x[2] + x[3];
  float q = x[0] * x[0] + x[1] * x[1] + x[2] * x[2] + x[3] * x[3];
#pragma unroll
  for (int o = 32; o >= 1; o >>= 1) { s += __shfl_xor(s, o); q += __shfl_xor(q, o); }
  float mean = s * (1.f / 256.f);
  float var = q * (1.f / 256.f) - mean * mean;
  float rs = rsqrtf(var + 1e-5f);
  u64 p = 0;
#pragma unroll
  for (int c = 0; c < 4; ++c) {
    int k = lane * 4 + c;
    float y = (x[c] - mean) * rs * gw[k] + gb[k];
    y = fmaxf(y, 0.f);
    p |= ((u64)f2bf(y)) << (16 * c);
  }
  *(u64*)(op + row * 256 + lane * 4) = p;
}

// ---------------------------------------------------------------- LSTM scan: wavefront over chain positions
// done[t]=1 resets h,c at START of step t => each row's window factors into independent
// chains. Per block (2 rows x 32 steps): build chains (ballot), sort by len desc;
// iteration p runs step p of every live chain as a DENSE M=16 gather-GEMM over an LDS
// h-store + dense cell update. No done-masking, no shuffles.
// h-store: [2 rows][34 slots][272B] (slot0 = carry h, slot33 = zeros, slot t+1 = h(t)).
// c lives in VGPRs: chain cr is ALWAYS handled by the lane with 4lq+r == cr mod 16
// (stable across p) -> creg[tb4][r], statically indexed via full tb unroll (rule #20).
// This deletes the 66KB LDS c-store: total LDS 18.9KB (< 64KB, no hipFuncSetAttribute).
// gin: dense rows -> quarter-wave gathers 32B contiguous (R6 frame layout was 25% sector
// efficiency -> 88MB fetch/dispatch; this is ~21MB).
// End of kernel: bulk-dump h-store -> global hs in the frag layout k_head expects.
struct ScanArgs {
  const u16 *gin0, *gin1;       // [Tseg*256][1024] bf16 (sign/log2e folded)
  const char *whq0, *whq1;      // [1024][256] i8
  const float *sr0, *sr1;       // [1024] f32 row scales (folded)
  const float *h00, *h01, *c00, *c01;   // [256][256] f32
  char *hs0, *hs1;              // [Tseg][16 frames][4096] i8 frag-order
  float *hsv0, *hsv1, *csv0, *csv1;     // [256][256] f32
  const int* done;
  int t0, Tseg;                 // Tseg == 32
};

#define HPITCH 272
#define HSLOT(slot, row) ((((row) * 34) + (slot)) * HPITCH)
#define SCAN_LDS (34 * 2 * HPITCH + 80 * 4 + 33 * 4)

__global__ __launch_bounds__(1024, 1) void k_scan(ScanArgs A) {
  const int bb = blockIdx.x & 127, br = blockIdx.x >> 7;
  const int rb = bb << 1;                // 2 batch rows per block
  const int tid = threadIdx.x;
  const int w = tid >> 6, lane = tid & 63, lm = lane & 15, lq = lane >> 4;
  const int jj = w * 16 + lm;            // this lane's hidden unit
  const int mbase = (bb & 7) * 2;        // frame row base within bbx frame

  extern __shared__ char dsm[];
  char* hst = dsm;                                   // [2][34][HPITCH]
  int* chinfo = (int*)(dsm + 34 * 2 * HPITCH);       // [80]
  int* cnt = chinfo + 80;                            // [33]; cnt[32] = nchains

  const char* whq = br ? A.whq1 : A.whq0;
  const float* srP = br ? A.sr1 : A.sr0;
  const u16* gin = br ? A.gin1 : A.gin0;
  const float* h0 = br ? A.h01 : A.h00;
  const float* c0 = br ? A.c01 : A.c00;
  char* hsg = (br ? A.hs1 : A.hs0) + (bb >> 3) * 4096;
  float* hsv = br ? A.hsv1 : A.hsv0;
  float* csv = br ? A.csv1 : A.csv0;
  const int lastT = A.Tseg - 1;

  // weight tiles VGPR-resident (64 regs): tile g -> gate rows g*256 + w*16 + lm
  intx4 wreg[4][4];
#pragma unroll
  for (int g = 0; g < 4; ++g)
#pragma unroll
    for (int kk = 0; kk < 4; ++kk)
      wreg[g][kk] =
          *(const intx4*)(whq + (size_t)(g * 256 + w * 16 + lm) * 256 + kk * 64 + lq * 16);

  float srw[4];
#pragma unroll
  for (int g = 0; g < 4; ++g) srw[g] = srP[g * 256 + jj];

  // ---- schedule build (wave 0): chains via ballot, rank-sort by len desc ----
  if (w == 0) {
    int row = lane >> 5, t = lane & 31;
    int dn = A.done[(size_t)(A.t0 + t) * 256 + rb + row];
    int isstart = (t == 0) || dn;
    u64 mask = __ballot(isstart ? 1 : 0);
    int desc = 0, key = -1;
    if (isstart) {
      u64 m2 = (lane == 63) ? 0ULL : (mask >> (lane + 1));
      int lim = (row + 1) * 32 - lane;   // distance to row end
      int d = lim;
      if (m2) { int z = (int)__ffsll((long long)m2); if (z < d) d = z; }
      int iszero = dn ? 1 : 0;           // t==0 && !done -> carry chain
      desc = t | (row << 8) | (iszero << 9) | (d << 16);
      key = (d << 8) | (63 - lane);
    }
    int rank = 0;
#pragma unroll 1
    for (int i = 0; i < 64; ++i) {
      int ok = __shfl(key, i);
      rank += (ok > key) ? 1 : 0;
    }
    if (isstart) chinfo[rank] = desc;
    int nch = __popcll(mask);
    for (int c = nch + lane; c < 80; c += 64)
      chinfo[c] = 0 | (0 << 8) | (1 << 9) | (0 << 16);   // safe pad: zero-type, len 0
    if (lane == 0) cnt[32] = nch;
  }
  // h-store slot0 (carry h quantized) + slot33 (zeros)
  if (tid < 512) {
    int row = tid >> 8, j = tid & 255;
    float hv = h0[(size_t)(rb + row) * 256 + j];
    hst[HSLOT(0, row) + j] = (char)q127(hv);
    hst[HSLOT(33, row) + j] = 0;
  }
  __syncthreads();

  // cnt[p] = #chains with len > p
  {
    int nch = cnt[32];
    if (tid < 32) {
      int c2 = 0;
      for (int c = 0; c < nch; ++c) c2 += ((chinfo[c] >> 16) > tid) ? 1 : 0;
      cnt[tid] = c2;
    }
  }

  // c state in VGPRs: creg[tb4][r] = c of chain cr = tb4*16 + 4*lq + r, hidden jj.
  // carry chains (t==0, iszero==0) init from c0; all others (incl. pads) start at 0.
  float creg[4][4];
#pragma unroll
  for (int tb4 = 0; tb4 < 4; ++tb4)
#pragma unroll
    for (int r = 0; r < 4; ++r) {
      int d = chinfo[tb4 * 16 + 4 * lq + r];
      float cv = 0.f;
      if (((d >> 9) & 1) == 0 && (d & 255) == 0)
        cv = c0[(size_t)(rb + ((d >> 8) & 1)) * 256 + jj];
      creg[tb4][r] = cv;
    }
  __syncthreads();

  const int maxp = chinfo[0] >> 16;   // longest chain

  for (int p = 0; p < maxp; ++p) {
    int Ap = cnt[p];
#pragma unroll
    for (int tb4 = 0; tb4 < 4; ++tb4) {
      const int tb = tb4 * 16;
      if (tb < Ap) {
        // A-gather descriptor for this lane's tile row (chain tb+lm)
        int dA = chinfo[tb + lm];
        int stA = dA & 255, rowA = (dA >> 8) & 1, zrA = (dA >> 9) & 1;
        int slot = (p == 0) ? (zrA ? 33 : 0) : (stA + p);
        int habase = HSLOT(slot, rowA);
        // per-r chain descs; issue gin loads early (hide latency under MFMA)
        int trr[4], rwr[4];
        u16 gld[4][4];
#pragma unroll
        for (int r = 0; r < 4; ++r) {
          int dr = chinfo[tb + 4 * lq + r];
          trr[r] = (dr & 255) + p;
          rwr[r] = (dr >> 8) & 1;
          unsigned off = ((unsigned)trr[r] * 256 + (unsigned)(rb + rwr[r])) * 1024 + jj;
          gld[r][0] = gin[off];
          gld[r][1] = gin[off + 256];
          gld[r][2] = gin[off + 512];
          gld[r][3] = gin[off + 768];
        }
        // dense MFMA: 16 x 16x16x64 i8 (A rows = 16 gathered chains)
        intx4 acc[4] = {};
#pragma unroll
        for (int kk = 0; kk < 4; ++kk) {
          intx4 af = *(const intx4*)&hst[habase + kk * 64 + lq * 16];
#pragma unroll
          for (int g = 0; g < 4; ++g)
            acc[g] = __builtin_amdgcn_mfma_i32_16x16x64_i8(af, wreg[g][kk], acc[g], 0, 0, 0);
        }
        // cells: lane handles chains tb+4lq+r (r=0..3), hidden jj, gates in-register
#pragma unroll
        for (int r = 0; r < 4; ++r) {
          if (tb + 4 * lq + r < Ap) {
            float xi = fmaf((float)acc[0][r], srw[0], bf2f(gld[r][0]));
            float xf = fmaf((float)acc[1][r], srw[1], bf2f(gld[r][1]));
            float xg = fmaf((float)acc[2][r], srw[2], bf2f(gld[r][2]));
            float xo = fmaf((float)acc[3][r], srw[3], bf2f(gld[r][3]));
            float ig = __builtin_amdgcn_rcpf(1.f + __builtin_amdgcn_exp2f(xi));
            float fg = __builtin_amdgcn_rcpf(1.f + __builtin_amdgcn_exp2f(xf));
            float gg = 1.f - 2.f * __builtin_amdgcn_rcpf(1.f + __builtin_amdgcn_exp2f(xg));
            float og = __builtin_amdgcn_rcpf(1.f + __builtin_amdgcn_exp2f(xo));
            float cn = fg * creg[tb4][r] + ig * gg;
            creg[tb4][r] = cn;
            float th = 1.f - 2.f * __builtin_amdgcn_rcpf(1.f + __builtin_amdgcn_exp2f(TWOLOG2E_F * cn));
            float hn = og * th;
            hst[HSLOT(trr[r] + 1, rwr[r]) + jj] = (char)q127(hn);
            if (trr[r] == lastT) {
              size_t idx = (size_t)(rb + rwr[r]) * 256 + jj;
              hsv[idx] = hn;
              csv[idx] = cn;
            }
          }
        }
      }
    }
    __syncthreads();   // h-store writes visible for next iteration's gathers
  }

  // bulk hs dump: slots 1..32 -> global frag layout (rows at m16 = (bb&7)*2 + row)
  {
    int t = tid >> 5, row = (tid >> 4) & 1, q = tid & 15;
    intx4 v = *(const intx4*)&hst[HSLOT(t + 1, row) + q * 16];
    char* dst = hsg + (size_t)t * 65536 + (q >> 2) * 1024 + (q & 3) * 256 + (mbase + row) * 16;
    *(intx4*)dst = v;
  }
}

// ---------------------------------------------------------------- heads: LN + policy/value + logprob/entropy
__global__ __launch_bounds__(256) void k_head(
    const char* __restrict__ hs_a, const char* __restrict__ hs_c,
    const float* __restrict__ a_lnw, const float* __restrict__ a_lnb,
    const float* __restrict__ c_lnw, const float* __restrict__ c_lnb,
    const float* __restrict__ mW, const float* __restrict__ mb,
    const float* __restrict__ logstd, const float* __restrict__ hW,
    const float* __restrict__ hb, const float* __restrict__ action,
    float* __restrict__ lp, float* __restrict__ ent, float* __restrict__ val,
    int row0) {
  __shared__ float smW[16][260];
  __shared__ float shW[256];
  __shared__ float spar[4][256];
  __shared__ float hrow[4][264];
  int tid = threadIdx.x;
  for (int i = tid; i < 4096; i += 256) smW[i >> 8][i & 255] = mW[i];
  shW[tid] = hW[tid];
  spar[0][tid] = a_lnw[tid]; spar[1][tid] = a_lnb[tid];
  spar[2][tid] = c_lnw[tid]; spar[3][tid] = c_lnb[tid];
  __syncthreads();

  int w = tid >> 6, lane = tid & 63, lm = lane & 15, lq = lane >> 4;
  float entc = 0.f;
#pragma unroll
  for (int j = 0; j < 16; ++j) entc += 0.5f + 0.5f * LOG2PI_F + logstd[j];
  float ls = logstd[lm];
  float sd = __expf(ls);
  float mbj = mb[lm];

  int rbase = (blockIdx.x * 4 + w) * 16;
  for (int rr = 0; rr < 16; ++rr) {
    int row = rbase + rr;
    int m = row & 15;
    size_t base = (size_t)(row >> 8) * 65536 + (size_t)((row >> 4) & 15) * 4096;
    int off = (lane >> 4) * 1024 + (m + 16 * ((lane >> 2) & 3)) * 16 + (lane & 3) * 4;
    int va = *(const int*)(hs_a + base + off);
    float x[4];
#pragma unroll
    for (int c = 0; c < 4; ++c) x[c] = (float)((va << (24 - 8 * c)) >> 24) * (1.f / 127.f);
    float s = x[0] + x[1] + x[2] + x[3];
    float q = x[0] * x[0] + x[1] * x[1] + x[2] * x[2] + x[3] * x[3];
#pragma unroll
    for (int o = 32; o >= 1; o >>= 1) { s += __shfl_xor(s, o); q += __shfl_xor(q, o); }
    float mean = s * (1.f / 256.f);
    float rs = rsqrtf(q * (1.f / 256.f) - mean * mean + 1e-5f);
    floatx4 hh;
#pragma unroll
    for (int c = 0; c < 4; ++c) {
      int k = lane * 4 + c;
      hh[c] = (x[c] - mean) * rs * spar[0][k] + spar[1][k];
    }
    *(floatx4*)&hrow[w][lane * 4] = hh;
    float p = 0.f;
#pragma unroll 16
    for (int k2 = 0; k2 < 64; ++k2) {
      int kx = lq * 64 + ((k2 + lq * 16) & 63);
      p = fmaf(hrow[w][kx], smW[lm][kx], p);
    }
    p += __shfl_xor(p, 16);
    p += __shfl_xor(p, 32);
    float meanj = p + mbj;
    float aj = action[(size_t)(row0 + row) * 16 + lm];
    float z = (aj - meanj) / sd;
    float term = -0.5f * z * z - ls - 0.5f * LOG2PI_F;
    term += __shfl_xor(term, 1);
    term += __shfl_xor(term, 2);
    term += __shfl_xor(term, 4);
    term += __shfl_xor(term, 8);
    int vc = *(const int*)(hs_c + base + off);
    float y[4];
#pragma unroll
    for (int c = 0; c < 4; ++c) y[c] = (float)((vc << (24 - 8 * c)) >> 24) * (1.f / 127.f);
    float s2 = y[0] + y[1] + y[2] + y[3];
    float q2 = y[0] * y[0] + y[1] * y[1] + y[2] * y[2] + y[3] * y[3];
#pragma unroll
    for (int o = 32; o >= 1; o >>= 1) { s2 += __shfl_xor(s2, o); q2 += __shfl_xor(q2, o); }
    float mean2 = s2 * (1.f / 256.f);
    float rs2 = rsqrtf(q2 * (1.f / 256.f) - mean2 * mean2 + 1e-5f);
    float pv = 0.f;
#pragma unroll
    for (int c = 0; c < 4; ++c) {
      int k = lane * 4 + c;
      float hc = (y[c] - mean2) * rs2 * spar[2][k] + spar[3][k];
      pv = fmaf(hc, shW[k], pv);
    }
#pragma unroll
    for (int o = 32; o >= 1; o >>= 1) pv += __shfl_xor(pv, o);
    if (lane == 0) {
      lp[row0 + row] = term;
      ent[row0 + row] = entc;
      val[row0 + row] = pv + hb[0];
    }
  }
}

// ---------------------------------------------------------------- host
extern "C" void kernel_launch(void* const* d_in, const int* in_sizes, int n_in,
                              void* d_out, int out_size, void* d_ws, size_t ws_size,
                              hipStream_t stream) {
  const int N = 131072, T = 512;
  const float* x = (const float*)d_in[0];
  const int* done = (const int*)d_in[1];
  const float* h0i[2] = {(const float*)d_in[2], (const float*)d_in[4]};
  const float* c0i[2] = {(const float*)d_in[3], (const float*)d_in[5]};
  const float* action = (const float*)d_in[6];
  const float *W1[2], *b1[2], *W2[2], *b2[2], *flnw[2], *flnb[2];
  const float *Wih[2], *Whh[2], *bih[2], *bhh[2], *lnw[2], *lnb[2];
  for (int br = 0; br < 2; ++br) {
    int o = 7 + br * 12;
    W1[br] = (const float*)d_in[o + 0];  b1[br] = (const float*)d_in[o + 1];
    W2[br] = (const float*)d_in[o + 2];  b2[br] = (const float*)d_in[o + 3];
    flnw[br] = (const float*)d_in[o + 4]; flnb[br] = (const float*)d_in[o + 5];
    Wih[br] = (const float*)d_in[o + 6]; Whh[br] = (const float*)d_in[o + 7];
    bih[br] = (const float*)d_in[o + 8]; bhh[br] = (const float*)d_in[o + 9];
    lnw[br] = (const float*)d_in[o + 10]; lnb[br] = (const float*)d_in[o + 11];
  }
  const float* mW = (const float*)d_in[31];
  const float* mb = (const float*)d_in[32];
  const float* logstd = (const float*)d_in[33];
  const float* hW = (const float*)d_in[34];
  const float* hb = (const float*)d_in[35];

  float* out = (float*)d_out;
  float* o_lp = out;
  float* o_ent = out + N;
  float* o_val = out + 2 * N;
  float* o_ah = out + 3 * N;
  float* o_ac = o_ah + 65536;
  float* o_ch = o_ac + 65536;
  float* o_cc = o_ch + 65536;

  // st fixed at 16 (chain-scan assumes Tseg==32); sr = MLP row segmentation:
  // pick the LARGEST segment that fits ws (fewer, bigger, launch-overhead-free MLP GEMMs).
  const long Ts = 32;
  auto rq = [&](long sr2) -> size_t {
    long Ms2 = N / sr2;
    size_t s = 0;
    auto al = [&](size_t b) { s += (b + 255) & ~(size_t)255; };
    al(2 * 65536 * 2); al(2 * 131072 * 2); al(2 * 262144 * 2);
    al(2 * 262144); al(2048 * 4);
    al(2 * 1024 * 4); al(2 * 512 * 4); al(2 * 256 * 4); al(1024 * 4);
    al(2 * 65536 * 4); al(2 * 65536 * 4);
    al((size_t)2 * Ms2 * 512 * 2);
    al((size_t)2 * Ms2 * 256 * 2);
    al((size_t)2 * N * 256 * 2);
    al((size_t)2 * Ts * 262144 * 2);
    al((size_t)2 * Ts * 65536);
    return s;
  };
  int sr = 16;
  const int cands[5] = {1, 2, 4, 8, 16};
  for (int i = 0; i < 5; ++i)
    if (rq(cands[i]) + ((size_t)4 << 20) <= ws_size) { sr = cands[i]; break; }
  const int st = 16;
  const long Ms = N / sr;

  char* pp = (char*)d_ws;
  auto carve = [&](size_t b) -> void* { void* r = pp; pp += (b + 255) & ~(size_t)255; return r; };
  u16* W1b = (u16*)carve(2 * 65536 * 2);
  u16* W2b = (u16*)carve(2 * 131072 * 2);
  u16* Wihb = (u16*)carve(2 * 262144 * 2);
  char* whhq = (char*)carve(2 * 262144);
  float* srowP = (float*)carve(2048 * 4);
  float* bihh = (float*)carve(2 * 1024 * 4);
  float* b1c = (float*)carve(2 * 512 * 4);
  float* b2c = (float*)carve(2 * 256 * 4);
  float* lnp = (float*)carve(1024 * 4);
  float* hsv = (float*)carve(2 * 65536 * 4);
  float* csv = (float*)carve(2 * 65536 * 4);
  u16* h1 = (u16*)carve((size_t)2 * Ms * 512 * 2);
  u16* g2 = (u16*)carve((size_t)2 * Ms * 256 * 2);
  u16* featP = (u16*)carve((size_t)2 * N * 256 * 2);
  u16* ginP = (u16*)carve((size_t)2 * Ts * 262144 * 2);
  char* hsbP = (char*)carve((size_t)2 * Ts * 65536);

  // prep
  PrepArgs pa{};
  int ns = 0, blk = 0;
  auto addseg = [&](const float* s1, const float* s2, void* d, int n, int mode) {
    pa.src[ns] = s1; pa.src2[ns] = s2; pa.dst[ns] = d; pa.mode[ns] = mode; pa.n[ns] = n;
    pa.blk0[ns] = blk; blk += (n + 1023) / 1024; ++ns;
  };
  for (int br = 0; br < 2; ++br) {
    addseg(W1[br], nullptr, W1b + br * 65536, 65536, 0);
    addseg(W2[br], nullptr, W2b + br * 131072, 131072, 0);
    addseg(Wih[br], nullptr, Wihb + br * 262144, 262144, 0);
    addseg(bih[br], bhh[br], bihh + br * 1024, 1024, 1);
    addseg(b1[br], nullptr, b1c + br * 512, 512, 2);
    addseg(b2[br], nullptr, b2c + br * 256, 256, 2);
    addseg(flnw[br], nullptr, lnp + br * 512, 256, 2);
    addseg(flnb[br], nullptr, lnp + br * 512 + 256, 256, 2);
  }
  pa.nseg = ns;
  pa.blk0[ns] = blk;
  k_prep<<<blk, 256, 0, stream>>>(pa);
  k_quant<<<512, 256, 0, stream>>>(Whh[0], Whh[1], whhq, srowP);

  // MLP features (row-segmented, branch z-batched)
  for (int s = 0; s < sr; ++s) {
    k_gemm<1, 1><<<dim3(4, Ms / 128, 2), 256, 0, stream>>>(
        x + (size_t)s * Ms * 128, W1b, b1c, h1, 512, 128, 1, 0,
        0L, 65536L, (long)Ms * 512);
    k_gemm<1, 0><<<dim3(2, Ms / 128, 2), 256, 0, stream>>>(
        h1, W2b, b2c, g2, 256, 512, 0, 0,
        (long)Ms * 512, 131072L, (long)Ms * 256);
    k_ln_relu<<<dim3(Ms / 4, 2), 256, 0, stream>>>(
        g2, lnp, featP + (size_t)s * Ms * 256, (long)Ms * 256, (long)N * 256);
  }

  // gin precompute + scan + heads (time-segmented)
  for (int s = 0; s < st; ++s) {
    long t0 = s * Ts;
    k_gemm<2, 0><<<dim3(8, Ts * 2, 2), 256, 0, stream>>>(
        featP + (size_t)t0 * 65536, Wihb, bihh, ginP, 1024, 256, 0, (int)Ts,
        (long)N * 256, 262144L, Ts * 262144L);
    ScanArgs sa;
    sa.gin0 = ginP; sa.gin1 = ginP + Ts * 262144;
    sa.whq0 = whhq; sa.whq1 = whhq + 262144;
    sa.sr0 = srowP; sa.sr1 = srowP + 1024;
    sa.h00 = s ? hsv : h0i[0]; sa.h01 = s ? hsv + 65536 : h0i[1];
    sa.c00 = s ? csv : c0i[0]; sa.c01 = s ? csv + 65536 : c0i[1];
    sa.hs0 = hsbP; sa.hs1 = hsbP + Ts * 65536;
    bool last = (s == st - 1);
    sa.hsv0 = last ? o_ah : hsv; sa.hsv1 = last ? o_ch : hsv + 65536;
    sa.csv0 = last ? o_ac : csv; sa.csv1 = last ? o_cc : csv + 65536;
    sa.done = done; sa.t0 = (int)t0; sa.Tseg = (int)Ts;
    k_scan<<<256, 1024, SCAN_LDS, stream>>>(sa);
    k_head<<<(int)(Ts * 256 / 64), 256, 0, stream>>>(
        hsbP, hsbP + Ts * 65536, lnw[0], lnb[0], lnw[1], lnb[1],
        mW, mb, logstd, hW, hb, action,
        o_lp, o_ent, o_val, (int)(t0 * 256));
  }
}

// Round 8
// 2402.822 us; speedup vs baseline: 1.1586x; 1.0611x over previous
//
#include <hip/hip_runtime.h>

typedef unsigned short u16;
typedef unsigned long long u64;
typedef __attribute__((ext_vector_type(8))) short short8;
typedef __attribute__((ext_vector_type(4))) float floatx4;
typedef __attribute__((ext_vector_type(4))) float f32x4;
typedef __attribute__((ext_vector_type(4))) int intx4;

#define LOG2PI_F 1.8378770664093453f
#define LOG2E_F 1.4426950408889634f
#define TWOLOG2E_F 2.8853900817779268f

__device__ inline float bf2f(u16 u) { return __uint_as_float(((unsigned)u) << 16); }
__device__ inline u16 f2bf(float f) {
  unsigned u = __float_as_uint(f);
  u += 0x7fff + ((u >> 16) & 1);   // RTNE
  return (u16)(u >> 16);
}
__device__ inline int q127(float f) {
  int qv = __float2int_rn(f * 127.f);
  return qv > 127 ? 127 : (qv < -127 ? -127 : qv);
}

// ---------------------------------------------------------------- prep: casts / adds / copies
struct PrepArgs {
  const float* src[18];
  const float* src2[18];
  void* dst[18];
  int mode[18];     // 0: f32->bf16, 1: f32+f32->f32, 2: f32 copy
  int n[18];
  int blk0[19];
  int nseg;
};

__global__ __launch_bounds__(256) void k_prep(PrepArgs a) {
  int b = blockIdx.x, s = 0;
  while (s + 1 < a.nseg && b >= a.blk0[s + 1]) ++s;
  int i = (b - a.blk0[s]) * 1024 + threadIdx.x * 4;
  if (i >= a.n[s]) return;
  if (a.mode[s] == 0) {
    f32x4 v = *(const f32x4*)(a.src[s] + i);
    u64 p = (u64)f2bf(v[0]) | ((u64)f2bf(v[1]) << 16)
          | ((u64)f2bf(v[2]) << 32) | ((u64)f2bf(v[3]) << 48);
    *(u64*)((u16*)a.dst[s] + i) = p;
  } else if (a.mode[s] == 1) {
    f32x4 x = *(const f32x4*)(a.src[s] + i);
    f32x4 y = *(const f32x4*)(a.src2[s] + i);
    *(f32x4*)((float*)a.dst[s] + i) = x + y;
  } else {
    *(f32x4*)((float*)a.dst[s] + i) = *(const f32x4*)(a.src[s] + i);
  }
}

// ---------------------------------------------------------------- Whh per-row int8 quantization
// sr = max/(127*127) * sign/log2e-fold: -log2e for i/f/o gates, +2*log2e for g gate.
__global__ __launch_bounds__(256) void k_quant(const float* __restrict__ w0,
                                               const float* __restrict__ w1,
                                               char* __restrict__ q, float* __restrict__ sr) {
  int tid = threadIdx.x, lane = tid & 63;
  int row = blockIdx.x * 4 + (tid >> 6);
  int br = row >> 10, r = row & 1023;
  const float* src = (br ? w1 : w0) + (size_t)r * 256 + lane * 4;
  f32x4 v = *(const f32x4*)src;
  float m = fmaxf(fmaxf(fabsf(v[0]), fabsf(v[1])), fmaxf(fabsf(v[2]), fabsf(v[3])));
#pragma unroll
  for (int o = 32; o >= 1; o >>= 1) m = fmaxf(m, __shfl_xor(m, o));
  float inv = m > 0.f ? 127.f / m : 0.f;
  int pk = 0;
#pragma unroll
  for (int c = 0; c < 4; ++c) {
    int qq = __float2int_rn(v[c] * inv);
    qq = qq > 127 ? 127 : (qq < -127 ? -127 : qq);
    pk |= (qq & 255) << (8 * c);
  }
  *(int*)(q + (size_t)row * 256 + lane * 4) = pk;
  if (lane == 0) {
    float sf = (r >= 512 && r < 768) ? TWOLOG2E_F : -LOG2E_F;
    sr[row] = m * (1.f / (127.f * 127.f)) * sf;
  }
}

// ---------------------------------------------------------------- GEMM: C = act(A @ W^T + bias), z = branch
template <int EPI, int AF32>
__global__ __launch_bounds__(256, 2) void k_gemm(
    const void* __restrict__ Agv, const u16* __restrict__ Wg,
    const float* __restrict__ biasP, void* __restrict__ outv,
    int Nn, int K, int relu, int Tseg,
    long az, long wz, long oz) {
  __shared__ u16 As[128][72];
  __shared__ u16 Ws[128][72];
  const int tid = threadIdx.x;
  const int z = blockIdx.z;
  const int bn = blockIdx.x * 128;
  const int bm = blockIdx.y * 128;
  const int w = tid >> 6, lane = tid & 63, lm = lane & 15, lq = lane >> 4;
  const int wr = (w >> 1) * 64, wc = (w & 1) * 64;
  const int tr = tid >> 3, tc = (tid & 7) * 8;

  const u16* Ab = (const u16*)Agv;
  const float* Af = (const float*)Agv;
  const u16* Wb = Wg + (size_t)z * wz;

  floatx4 acc[4][4] = {};

  for (int k0 = 0; k0 < K; k0 += 64) {
    __syncthreads();
#pragma unroll
    for (int rr = 0; rr < 4; ++rr) {
      int row = rr * 32 + tr;
      if (AF32) {
        const float* src = Af + (size_t)z * az + (size_t)(bm + row) * K + k0 + tc;
        f32x4 v0 = *(const f32x4*)src;
        f32x4 v1 = *(const f32x4*)(src + 4);
        short8 sv;
#pragma unroll
        for (int c = 0; c < 4; ++c) { sv[c] = (short)f2bf(v0[c]); sv[4 + c] = (short)f2bf(v1[c]); }
        *(short8*)&As[row][tc] = sv;
      } else {
        *(short8*)&As[row][tc] = *(const short8*)(Ab + (size_t)z * az + (size_t)(bm + row) * K + k0 + tc);
      }
      *(short8*)&Ws[row][tc] = *(const short8*)(Wb + (size_t)(bn + row) * K + k0 + tc);
    }
    __syncthreads();
#pragma unroll
    for (int kk = 0; kk < 2; ++kk) {
      short8 a4[4], b4[4];
#pragma unroll
      for (int i = 0; i < 4; ++i) {
        a4[i] = *(const short8*)&As[wr + i * 16 + lm][kk * 32 + lq * 8];
        b4[i] = *(const short8*)&Ws[wc + i * 16 + lm][kk * 32 + lq * 8];
      }
#pragma unroll
      for (int i = 0; i < 4; ++i)
#pragma unroll
        for (int j = 0; j < 4; ++j)
          acc[i][j] = __builtin_amdgcn_mfma_f32_16x16x32_bf16(a4[i], b4[j], acc[i][j], 0, 0, 0);
    }
  }

#pragma unroll
  for (int i = 0; i < 4; ++i) {
#pragma unroll
    for (int j = 0; j < 4; ++j) {
      int col = bn + wc + j * 16 + lm;
      float bv = biasP[(size_t)z * Nn + col];
      float v[4];
#pragma unroll
      for (int r = 0; r < 4; ++r) {
        float t = acc[i][j][r] + bv;
        v[r] = relu ? fmaxf(t, 0.f) : t;
      }
      int row0l = bm + wr + i * 16 + lq * 4;
      if (EPI == 1) {
        u16* o = (u16*)outv + (size_t)z * oz;
#pragma unroll
        for (int r = 0; r < 4; ++r) o[(size_t)(row0l + r) * Nn + col] = f2bf(v[r]);
      } else {
        // gin: dense [t*256+row][1024] bf16 rows; R5<->R6 A/B bounded these scalar
        // stores at ~11us total. gate-fold: i/f/o * -log2e, g * +2*log2e.
        float s = (col >= 512 && col < 768) ? TWOLOG2E_F : -LOG2E_F;
        u16* o = (u16*)outv + (size_t)z * oz;
#pragma unroll
        for (int r = 0; r < 4; ++r) o[(size_t)(row0l + r) * Nn + col] = f2bf(v[r] * s);
      }
    }
  }
}

// ---------------------------------------------------------------- LayerNorm + relu -> bf16 (feature LN), z-batched
__global__ __launch_bounds__(256) void k_ln_relu(const u16* __restrict__ in,
                                                 const float* __restrict__ lnp,
                                                 u16* __restrict__ out,
                                                 long inz, long outz) {
  int z = blockIdx.y;
  int w = threadIdx.x >> 6, lane = threadIdx.x & 63;
  size_t row = (size_t)blockIdx.x * 4 + w;
  const u16* ip = in + (size_t)z * inz;
  u16* op = out + (size_t)z * outz;
  const float* gw = lnp + (size_t)z * 512;
  const float* gb = gw + 256;
  u64 hv = *(const u64*)(ip + row * 256 + lane * 4);
  float x[4];
#pragma unroll
  for (int c = 0; c < 4; ++c) x[c] = bf2f((u16)(hv >> (16 * c)));
  float s = x[0] + x[1] + x[2] + x[3];
  float q = x[0] * x[0] + x[1] * x[1] + x[2] * x[2] + x[3] * x[3];
#pragma unroll
  for (int o = 32; o >= 1; o >>= 1) { s += __shfl_xor(s, o); q += __shfl_xor(q, o); }
  float mean = s * (1.f / 256.f);
  float var = q * (1.f / 256.f) - mean * mean;
  float rs = rsqrtf(var + 1e-5f);
  u64 p = 0;
#pragma unroll
  for (int c = 0; c < 4; ++c) {
    int k = lane * 4 + c;
    float y = (x[c] - mean) * rs * gw[k] + gb[k];
    y = fmaxf(y, 0.f);
    p |= ((u64)f2bf(y)) << (16 * c);
  }
  *(u64*)(op + row * 256 + lane * 4) = p;
}

// ---------------------------------------------------------------- LSTM scan: wavefront over chain positions
// R5-verbatim core (measured 58.5us, WRITE 5.1MB -> no scratch): LDS c-store, runtime
// tile loop (#pragma unroll 1 + break -> one tile's temporaries live at a time; the R7
// full-unroll VGPR-c variant spilled: WRITE 38MB scratch traffic).
// done[t]=1 resets h,c at START of step t => chains; iteration p runs step p of every
// live chain as a DENSE M=16 gather-GEMM over the LDS h-store + dense cell update.
// h-store: [34 slots][2 rows][272B] (slot0 = carry h, slot33 = zeros, slot t+1 = h(t)).
// c-store: [64 chains][260 f32] LDS. gin: dense [t*256+row][1024] bf16.
struct ScanArgs {
  const u16 *gin0, *gin1;       // [Tseg*256][1024] bf16 (sign/log2e folded)
  const char *whq0, *whq1;      // [1024][256] i8
  const float *sr0, *sr1;       // [1024] f32 row scales (folded)
  const float *h00, *h01, *c00, *c01;   // [256][256] f32
  char *hs0, *hs1;              // [Tseg][16 frames][4096] i8 frag-order
  float *hsv0, *hsv1, *csv0, *csv1;     // [256][256] f32
  const int* done;
  int t0, Tseg;                 // Tseg == 32
};

#define HPITCH 272
#define CPITCH 260
#define SCAN_LDS (34 * 2 * HPITCH + 64 * CPITCH * 4 + 80 * 4 + 33 * 4)

__global__ __launch_bounds__(1024, 1) void k_scan(ScanArgs A) {
  const int bb = blockIdx.x & 127, br = blockIdx.x >> 7;
  const int rb = bb << 1;                // 2 batch rows per block
  const int tid = threadIdx.x;
  const int w = tid >> 6, lane = tid & 63, lm = lane & 15, lq = lane >> 4;
  const int jj = w * 16 + lm;            // this lane's hidden unit

  extern __shared__ char dsm[];
  char* hst = dsm;                                   // [34*2][HPITCH]
  float* cst = (float*)(dsm + 34 * 2 * HPITCH);      // [64][CPITCH]
  int* chinfo = (int*)(dsm + 34 * 2 * HPITCH + 64 * CPITCH * 4);  // [80]
  int* cnt = chinfo + 80;                            // [33]; cnt[32] = nchains

  const char* whq = br ? A.whq1 : A.whq0;
  const float* srP = br ? A.sr1 : A.sr0;
  const u16* gin = br ? A.gin1 : A.gin0;
  const float* h0 = br ? A.h01 : A.h00;
  const float* c0 = br ? A.c01 : A.c00;
  char* hsg = (br ? A.hs1 : A.hs0) + (bb >> 3) * 4096;
  float* hsv = br ? A.hsv1 : A.hsv0;
  float* csv = br ? A.csv1 : A.csv0;
  const int lastT = A.Tseg - 1;

  // weight tiles VGPR-resident (64 regs): tile g -> gate rows g*256 + w*16 + lm
  intx4 wreg[4][4];
#pragma unroll
  for (int g = 0; g < 4; ++g)
#pragma unroll
    for (int kk = 0; kk < 4; ++kk)
      wreg[g][kk] =
          *(const intx4*)(whq + (size_t)(g * 256 + w * 16 + lm) * 256 + kk * 64 + lq * 16);

  float srw[4];
#pragma unroll
  for (int g = 0; g < 4; ++g) srw[g] = srP[g * 256 + jj];

  // ---- schedule build (wave 0): chains via ballot, rank-sort by len desc ----
  if (w == 0) {
    int row = lane >> 5, t = lane & 31;
    int dn = A.done[(size_t)(A.t0 + t) * 256 + rb + row];
    int isstart = (t == 0) || dn;
    u64 mask = __ballot(isstart ? 1 : 0);
    int desc = 0, key = -1;
    if (isstart) {
      u64 m2 = (lane == 63) ? 0ULL : (mask >> (lane + 1));
      int lim = (row + 1) * 32 - lane;   // distance to row end
      int d = lim;
      if (m2) { int z = (int)__ffsll((long long)m2); if (z < d) d = z; }
      int iszero = dn ? 1 : 0;           // t==0 && !done -> carry chain
      desc = t | (row << 8) | (iszero << 9) | (d << 16);
      key = (d << 8) | (63 - lane);
    }
    int rank = 0;
#pragma unroll 1
    for (int i = 0; i < 64; ++i) {
      int ok = __shfl(key, i);
      rank += (ok > key) ? 1 : 0;
    }
    if (isstart) chinfo[rank] = desc;
    int nch = __popcll(mask);
    for (int c = nch + lane; c < 80; c += 64)
      chinfo[c] = 0 | (0 << 8) | (1 << 9) | (0 << 16);   // safe pad: zero-type, len 0
    if (lane == 0) cnt[32] = nch;
  }
  // zero c-store
  for (int i = tid; i < 64 * CPITCH; i += 1024) cst[i] = 0.f;
  // h-store slot0 (carry h quantized) + slot33 (zeros)
  if (tid < 512) {
    int row = tid >> 8, j = tid & 255;
    float hv = h0[(size_t)(rb + row) * 256 + j];
    hst[(0 * 2 + row) * HPITCH + j] = (char)q127(hv);
    hst[(33 * 2 + row) * HPITCH + j] = 0;
  }
  __syncthreads();

  // cnt[p] = #chains with len > p; carry-chain c init
  {
    int nch = cnt[32];
    if (tid < 32) {
      int c2 = 0;
      for (int c = 0; c < nch; ++c) c2 += ((chinfo[c] >> 16) > tid) ? 1 : 0;
      cnt[tid] = c2;
    }
#pragma unroll 1
    for (int c04 = 0; c04 < 64; c04 += 4) {
      int c = c04 + (tid >> 8);
      if (c < nch) {
        int d = chinfo[c];
        if (((d >> 9) & 1) == 0 && (d & 255) == 0) {   // carry chain
          int row = (d >> 8) & 1, j = tid & 255;
          cst[c * CPITCH + j] = c0[(size_t)(rb + row) * 256 + j];
        }
      }
    }
  }
  __syncthreads();

  const int maxp = chinfo[0] >> 16;   // longest chain

  for (int p = 0; p < maxp; ++p) {
    int Ap = cnt[p];
#pragma unroll 1
    for (int tb = 0; tb < 64; tb += 16) {
      if (tb >= Ap) break;
      // A-gather descriptor for this lane's tile row (chain tb+lm)
      int dA = chinfo[tb + lm];
      int stA = dA & 255, rowA = (dA >> 8) & 1, zrA = (dA >> 9) & 1;
      int slot = (p == 0) ? (zrA ? 33 : 0) : (stA + p);
      int habase = (slot * 2 + rowA) * HPITCH;
      // per-r chain descs; issue gin + c loads early (hide latency under MFMA)
      int trr[4], rwr[4], crv[4];
      u16 gld[4][4];
      float cpr[4];
#pragma unroll
      for (int r = 0; r < 4; ++r) {
        int cr = tb + 4 * lq + r;
        crv[r] = cr;
        int dr = chinfo[cr];
        trr[r] = (dr & 255) + p;
        rwr[r] = (dr >> 8) & 1;
        unsigned off = ((unsigned)trr[r] * 256 + (unsigned)(rb + rwr[r])) * 1024 + jj;
        gld[r][0] = gin[off];
        gld[r][1] = gin[off + 256];
        gld[r][2] = gin[off + 512];
        gld[r][3] = gin[off + 768];
        cpr[r] = cst[cr * CPITCH + jj];
      }
      // dense MFMA: 16 x 16x16x64 i8 (A rows = 16 gathered chains)
      intx4 acc[4] = {};
#pragma unroll
      for (int kk = 0; kk < 4; ++kk) {
        intx4 af = *(const intx4*)&hst[habase + kk * 64 + lq * 16];
#pragma unroll
        for (int g = 0; g < 4; ++g)
          acc[g] = __builtin_amdgcn_mfma_i32_16x16x64_i8(af, wreg[g][kk], acc[g], 0, 0, 0);
      }
      // cells: lane handles chains tb+4lq+r (r=0..3), hidden jj, gates in-register
#pragma unroll
      for (int r = 0; r < 4; ++r) {
        if (crv[r] < Ap) {
          float xi = fmaf((float)acc[0][r], srw[0], bf2f(gld[r][0]));
          float xf = fmaf((float)acc[1][r], srw[1], bf2f(gld[r][1]));
          float xg = fmaf((float)acc[2][r], srw[2], bf2f(gld[r][2]));
          float xo = fmaf((float)acc[3][r], srw[3], bf2f(gld[r][3]));
          float ig = __builtin_amdgcn_rcpf(1.f + __builtin_amdgcn_exp2f(xi));
          float fg = __builtin_amdgcn_rcpf(1.f + __builtin_amdgcn_exp2f(xf));
          float gg = 1.f - 2.f * __builtin_amdgcn_rcpf(1.f + __builtin_amdgcn_exp2f(xg));
          float og = __builtin_amdgcn_rcpf(1.f + __builtin_amdgcn_exp2f(xo));
          float cn = fg * cpr[r] + ig * gg;
          float th = 1.f - 2.f * __builtin_amdgcn_rcpf(1.f + __builtin_amdgcn_exp2f(TWOLOG2E_F * cn));
          float hn = og * th;
          cst[crv[r] * CPITCH + jj] = cn;
          hst[((trr[r] + 1) * 2 + rwr[r]) * HPITCH + jj] = (char)q127(hn);
          if (trr[r] == lastT) {
            size_t idx = (size_t)(rb + rwr[r]) * 256 + jj;
            hsv[idx] = hn;
            csv[idx] = cn;
          }
        }
      }
    }
    __syncthreads();   // h-store writes visible for next iteration's gathers
  }

  // bulk hs dump: slots 1..32 -> global frag layout (rows at m16 = (bb&7)*2 + row)
  {
    int t = tid >> 5, row = (tid >> 4) & 1, q = tid & 15;
    intx4 v = *(const intx4*)&hst[((t + 1) * 2 + row) * HPITCH + q * 16];
    char* dst = hsg + (size_t)t * 65536 + (q >> 2) * 1024 + (q & 3) * 256 + ((bb & 7) * 2 + row) * 16;
    *(intx4*)dst = v;
  }
}

// ---------------------------------------------------------------- heads: LN + policy/value + logprob/entropy
__global__ __launch_bounds__(256) void k_head(
    const char* __restrict__ hs_a, const char* __restrict__ hs_c,
    const float* __restrict__ a_lnw, const float* __restrict__ a_lnb,
    const float* __restrict__ c_lnw, const float* __restrict__ c_lnb,
    const float* __restrict__ mW, const float* __restrict__ mb,
    const float* __restrict__ logstd, const float* __restrict__ hW,
    const float* __restrict__ hb, const float* __restrict__ action,
    float* __restrict__ lp, float* __restrict__ ent, float* __restrict__ val,
    int row0) {
  __shared__ float smW[16][260];
  __shared__ float shW[256];
  __shared__ float spar[4][256];
  __shared__ float hrow[4][264];
  int tid = threadIdx.x;
  for (int i = tid; i < 4096; i += 256) smW[i >> 8][i & 255] = mW[i];
  shW[tid] = hW[tid];
  spar[0][tid] = a_lnw[tid]; spar[1][tid] = a_lnb[tid];
  spar[2][tid] = c_lnw[tid]; spar[3][tid] = c_lnb[tid];
  __syncthreads();

  int w = tid >> 6, lane = tid & 63, lm = lane & 15, lq = lane >> 4;
  float entc = 0.f;
#pragma unroll
  for (int j = 0; j < 16; ++j) entc += 0.5f + 0.5f * LOG2PI_F + logstd[j];
  float ls = logstd[lm];
  float sd = __expf(ls);
  float mbj = mb[lm];

  int rbase = (blockIdx.x * 4 + w) * 16;
  for (int rr = 0; rr < 16; ++rr) {
    int row = rbase + rr;
    int m = row & 15;
    size_t base = (size_t)(row >> 8) * 65536 + (size_t)((row >> 4) & 15) * 4096;
    int off = (lane >> 4) * 1024 + (m + 16 * ((lane >> 2) & 3)) * 16 + (lane & 3) * 4;
    int va = *(const int*)(hs_a + base + off);
    float x[4];
#pragma unroll
    for (int c = 0; c < 4; ++c) x[c] = (float)((va << (24 - 8 * c)) >> 24) * (1.f / 127.f);
    float s = x[0] + x[1] + x[2] + x[3];
    float q = x[0] * x[0] + x[1] * x[1] + x[2] * x[2] + x[3] * x[3];
#pragma unroll
    for (int o = 32; o >= 1; o >>= 1) { s += __shfl_xor(s, o); q += __shfl_xor(q, o); }
    float mean = s * (1.f / 256.f);
    float rs = rsqrtf(q * (1.f / 256.f) - mean * mean + 1e-5f);
    floatx4 hh;
#pragma unroll
    for (int c = 0; c < 4; ++c) {
      int k = lane * 4 + c;
      hh[c] = (x[c] - mean) * rs * spar[0][k] + spar[1][k];
    }
    *(floatx4*)&hrow[w][lane * 4] = hh;
    float p = 0.f;
#pragma unroll 16
    for (int k2 = 0; k2 < 64; ++k2) {
      int kx = lq * 64 + ((k2 + lq * 16) & 63);
      p = fmaf(hrow[w][kx], smW[lm][kx], p);
    }
    p += __shfl_xor(p, 16);
    p += __shfl_xor(p, 32);
    float meanj = p + mbj;
    float aj = action[(size_t)(row0 + row) * 16 + lm];
    float z = (aj - meanj) / sd;
    float term = -0.5f * z * z - ls - 0.5f * LOG2PI_F;
    term += __shfl_xor(term, 1);
    term += __shfl_xor(term, 2);
    term += __shfl_xor(term, 4);
    term += __shfl_xor(term, 8);
    int vc = *(const int*)(hs_c + base + off);
    float y[4];
#pragma unroll
    for (int c = 0; c < 4; ++c) y[c] = (float)((vc << (24 - 8 * c)) >> 24) * (1.f / 127.f);
    float s2 = y[0] + y[1] + y[2] + y[3];
    float q2 = y[0] * y[0] + y[1] * y[1] + y[2] * y[2] + y[3] * y[3];
#pragma unroll
    for (int o = 32; o >= 1; o >>= 1) { s2 += __shfl_xor(s2, o); q2 += __shfl_xor(q2, o); }
    float mean2 = s2 * (1.f / 256.f);
    float rs2 = rsqrtf(q2 * (1.f / 256.f) - mean2 * mean2 + 1e-5f);
    float pv = 0.f;
#pragma unroll
    for (int c = 0; c < 4; ++c) {
      int k = lane * 4 + c;
      float hc = (y[c] - mean2) * rs2 * spar[2][k] + spar[3][k];
      pv = fmaf(hc, shW[k], pv);
    }
#pragma unroll
    for (int o = 32; o >= 1; o >>= 1) pv += __shfl_xor(pv, o);
    if (lane == 0) {
      lp[row0 + row] = term;
      ent[row0 + row] = entc;
      val[row0 + row] = pv + hb[0];
    }
  }
}

// ---------------------------------------------------------------- host (R4 structure; st fixed 16)
extern "C" void kernel_launch(void* const* d_in, const int* in_sizes, int n_in,
                              void* d_out, int out_size, void* d_ws, size_t ws_size,
                              hipStream_t stream) {
  const int N = 131072, T = 512;
  const float* x = (const float*)d_in[0];
  const int* done = (const int*)d_in[1];
  const float* h0i[2] = {(const float*)d_in[2], (const float*)d_in[4]};
  const float* c0i[2] = {(const float*)d_in[3], (const float*)d_in[5]};
  const float* action = (const float*)d_in[6];
  const float *W1[2], *b1[2], *W2[2], *b2[2], *flnw[2], *flnb[2];
  const float *Wih[2], *Whh[2], *bih[2], *bhh[2], *lnw[2], *lnb[2];
  for (int br = 0; br < 2; ++br) {
    int o = 7 + br * 12;
    W1[br] = (const float*)d_in[o + 0];  b1[br] = (const float*)d_in[o + 1];
    W2[br] = (const float*)d_in[o + 2];  b2[br] = (const float*)d_in[o + 3];
    flnw[br] = (const float*)d_in[o + 4]; flnb[br] = (const float*)d_in[o + 5];
    Wih[br] = (const float*)d_in[o + 6]; Whh[br] = (const float*)d_in[o + 7];
    bih[br] = (const float*)d_in[o + 8]; bhh[br] = (const float*)d_in[o + 9];
    lnw[br] = (const float*)d_in[o + 10]; lnb[br] = (const float*)d_in[o + 11];
  }
  const float* mW = (const float*)d_in[31];
  const float* mb = (const float*)d_in[32];
  const float* logstd = (const float*)d_in[33];
  const float* hW = (const float*)d_in[34];
  const float* hb = (const float*)d_in[35];

  float* out = (float*)d_out;
  float* o_lp = out;
  float* o_ent = out + N;
  float* o_val = out + 2 * N;
  float* o_ah = out + 3 * N;
  float* o_ac = o_ah + 65536;
  float* o_ch = o_ac + 65536;
  float* o_cc = o_ch + 65536;

  // tier selection (R4 structure); st fixed at 16 (chain scan needs Tseg==32),
  // sr = largest MLP row segment that fits ws.
  const long Ts = 32;
  auto rq = [&](long sr2) -> size_t {
    long Ms2 = N / sr2;
    size_t s = 0;
    auto al = [&](size_t b) { s += (b + 255) & ~(size_t)255; };
    al(2 * 65536 * 2); al(2 * 131072 * 2); al(2 * 262144 * 2);
    al(2 * 262144); al(2048 * 4);
    al(2 * 1024 * 4); al(2 * 512 * 4); al(2 * 256 * 4); al(1024 * 4);
    al(2 * 65536 * 4); al(2 * 65536 * 4);
    al((size_t)2 * Ms2 * 512 * 2);
    al((size_t)2 * Ms2 * 256 * 2);
    al((size_t)2 * N * 256 * 2);
    al((size_t)2 * Ts * 262144 * 2);
    al((size_t)2 * Ts * 65536);
    return s;
  };
  int sr = 16;
  const int cands[5] = {1, 2, 4, 8, 16};
  for (int i = 0; i < 5; ++i)
    if (rq(cands[i]) + ((size_t)4 << 20) <= ws_size) { sr = cands[i]; break; }
  const int st = 16;
  const long Ms = N / sr;

  char* pp = (char*)d_ws;
  auto carve = [&](size_t b) -> void* { void* r = pp; pp += (b + 255) & ~(size_t)255; return r; };
  u16* W1b = (u16*)carve(2 * 65536 * 2);
  u16* W2b = (u16*)carve(2 * 131072 * 2);
  u16* Wihb = (u16*)carve(2 * 262144 * 2);
  char* whhq = (char*)carve(2 * 262144);
  float* srowP = (float*)carve(2048 * 4);
  float* bihh = (float*)carve(2 * 1024 * 4);
  float* b1c = (float*)carve(2 * 512 * 4);
  float* b2c = (float*)carve(2 * 256 * 4);
  float* lnp = (float*)carve(1024 * 4);
  float* hsv = (float*)carve(2 * 65536 * 4);
  float* csv = (float*)carve(2 * 65536 * 4);
  u16* h1 = (u16*)carve((size_t)2 * Ms * 512 * 2);
  u16* g2 = (u16*)carve((size_t)2 * Ms * 256 * 2);
  u16* featP = (u16*)carve((size_t)2 * N * 256 * 2);
  u16* ginP = (u16*)carve((size_t)2 * Ts * 262144 * 2);
  char* hsbP = (char*)carve((size_t)2 * Ts * 65536);

  // prep
  PrepArgs pa{};
  int ns = 0, blk = 0;
  auto addseg = [&](const float* s1, const float* s2, void* d, int n, int mode) {
    pa.src[ns] = s1; pa.src2[ns] = s2; pa.dst[ns] = d; pa.mode[ns] = mode; pa.n[ns] = n;
    pa.blk0[ns] = blk; blk += (n + 1023) / 1024; ++ns;
  };
  for (int br = 0; br < 2; ++br) {
    addseg(W1[br], nullptr, W1b + br * 65536, 65536, 0);
    addseg(W2[br], nullptr, W2b + br * 131072, 131072, 0);
    addseg(Wih[br], nullptr, Wihb + br * 262144, 262144, 0);
    addseg(bih[br], bhh[br], bihh + br * 1024, 1024, 1);
    addseg(b1[br], nullptr, b1c + br * 512, 512, 2);
    addseg(b2[br], nullptr, b2c + br * 256, 256, 2);
    addseg(flnw[br], nullptr, lnp + br * 512, 256, 2);
    addseg(flnb[br], nullptr, lnp + br * 512 + 256, 256, 2);
  }
  pa.nseg = ns;
  pa.blk0[ns] = blk;
  k_prep<<<blk, 256, 0, stream>>>(pa);
  k_quant<<<512, 256, 0, stream>>>(Whh[0], Whh[1], whhq, srowP);

  // scan needs >64KB dynamic LDS (85.5KB) — attribute set like R4 (rest=531 with it)
  hipFuncSetAttribute((const void*)&k_scan, hipFuncAttributeMaxDynamicSharedMemorySize,
                      ((SCAN_LDS + 255) & ~255));

  // MLP features (row-segmented, branch z-batched)
  for (int s = 0; s < sr; ++s) {
    k_gemm<1, 1><<<dim3(4, Ms / 128, 2), 256, 0, stream>>>(
        x + (size_t)s * Ms * 128, W1b, b1c, h1, 512, 128, 1, 0,
        0L, 65536L, (long)Ms * 512);
    k_gemm<1, 0><<<dim3(2, Ms / 128, 2), 256, 0, stream>>>(
        h1, W2b, b2c, g2, 256, 512, 0, 0,
        (long)Ms * 512, 131072L, (long)Ms * 256);
    k_ln_relu<<<dim3(Ms / 4, 2), 256, 0, stream>>>(
        g2, lnp, featP + (size_t)s * Ms * 256, (long)Ms * 256, (long)N * 256);
  }

  // gin precompute + scan + heads (time-segmented)
  for (int s = 0; s < st; ++s) {
    long t0 = s * Ts;
    k_gemm<2, 0><<<dim3(8, Ts * 2, 2), 256, 0, stream>>>(
        featP + (size_t)t0 * 65536, Wihb, bihh, ginP, 1024, 256, 0, (int)Ts,
        (long)N * 256, 262144L, Ts * 262144L);
    ScanArgs sa;
    sa.gin0 = ginP; sa.gin1 = ginP + Ts * 262144;
    sa.whq0 = whhq; sa.whq1 = whhq + 262144;
    sa.sr0 = srowP; sa.sr1 = srowP + 1024;
    sa.h00 = s ? hsv : h0i[0]; sa.h01 = s ? hsv + 65536 : h0i[1];
    sa.c00 = s ? csv : c0i[0]; sa.c01 = s ? csv + 65536 : c0i[1];
    sa.hs0 = hsbP; sa.hs1 = hsbP + Ts * 65536;
    bool last = (s == st - 1);
    sa.hsv0 = last ? o_ah : hsv; sa.hsv1 = last ? o_ch : hsv + 65536;
    sa.csv0 = last ? o_ac : csv; sa.csv1 = last ? o_cc : csv + 65536;
    sa.done = done; sa.t0 = (int)t0; sa.Tseg = (int)Ts;
    k_scan<<<256, 1024, ((SCAN_LDS + 255) & ~255), stream>>>(sa);
    k_head<<<(int)(Ts * 256 / 64), 256, 0, stream>>>(
        hsbP, hsbP + Ts * 65536, lnw[0], lnb[0], lnw[1], lnb[1],
        mW, mb, logstd, hW, hb, action,
        o_lp, o_ent, o_val, (int)(t0 * 256));
  }
}